// Round 18
// baseline (247.259 us; speedup 1.0000x reference)
//
#include <hip/hip_runtime.h>
#include <cstdint>

#define TB 2048     // T
#define DIM 2560    // D
#define NQ 8
#define NKV 4
#define HDIM 256
#define WIN 1024
#define KMASK -2.3819763e+38f

using f32x4 = __attribute__((ext_vector_type(4))) float;
using s16x8 = __attribute__((ext_vector_type(8))) short;
using u16x4 = __attribute__((ext_vector_type(4))) unsigned short;

__device__ __forceinline__ unsigned short f2bf(float f) {
  uint32_t x = __builtin_bit_cast(uint32_t, f);
  x += 0x7FFFu + ((x >> 16) & 1u);
  return (unsigned short)(x >> 16);
}

__device__ __forceinline__ float bf2f(unsigned short u) {
  uint32_t x = (uint32_t)u << 16;
  return __builtin_bit_cast(float, x);
}

// ---------- fused prep: W1 pack (blocks 0..10239), W3 transpose (10240..15359),
// ---------- x f32->bf16 (15360..25599) ----------
__global__ __launch_bounds__(256) void k_prep(const float* __restrict__ q_w,
                                              const float* __restrict__ kv_w,
                                              const float* __restrict__ out_w,
                                              const float* __restrict__ x,
                                              unsigned short* __restrict__ W1,
                                              unsigned short* __restrict__ W3,
                                              unsigned short* __restrict__ XB) {
  __shared__ float tile[32][33];
  const int bi = blockIdx.x;
  const int tid = threadIdx.x;
  if (bi < 10240) {
    // ---- pack W1: head hd of (DIM x HDIM) f32 -> W1[c][d] bf16 ----
    const int hd = bi / 640;
    const int rem = bi % 640;
    const int r0 = (rem / 8) * 32, c0 = (rem % 8) * 32;
    const float* src = (hd < 8) ? (q_w + (size_t)hd * DIM * HDIM)
                                : (kv_w + (size_t)(hd - 8) * DIM * HDIM);
    unsigned short* dst = W1 + (size_t)hd * HDIM * DIM;
    const int tx = tid & 31, ty = tid >> 5;
#pragma unroll
    for (int i = 0; i < 32; i += 8)
      tile[ty + i][tx] = src[(size_t)(r0 + ty + i) * HDIM + c0 + tx];
    __syncthreads();
#pragma unroll
    for (int i = 0; i < 32; i += 8)
      dst[(size_t)(c0 + ty + i) * DIM + r0 + tx] = f2bf(tile[tx][ty + i]);
  } else if (bi < 15360) {
    // ---- transpose out_w f32 (2048 x 2560) -> W3 bf16 (2560 x 2048) ----
    const int j = bi - 10240;
    const int c0 = (j % 80) * 32, r0 = (j / 80) * 32;
    const int tx = tid & 31, ty = tid >> 5;
#pragma unroll
    for (int i = 0; i < 32; i += 8)
      tile[ty + i][tx] = out_w[(size_t)(r0 + ty + i) * DIM + c0 + tx];
    __syncthreads();
#pragma unroll
    for (int i = 0; i < 32; i += 8)
      W3[(size_t)(c0 + ty + i) * 2048 + r0 + tx] = f2bf(tile[tx][ty + i]);
  } else {
    // ---- x f32 -> bf16, 4 elems/thread ----
    const int j = bi - 15360;
    int i = j * 256 + tid;
    f32x4 v = *(const f32x4*)&x[(size_t)i * 4];
    u16x4 o;
#pragma unroll
    for (int k = 0; k < 4; ++k) o[k] = f2bf(v[k]);
    *(u16x4*)&XB[(size_t)i * 4] = o;
  }
}

// ---------- 256x256 tile bf16 GEMM, 4-phase schedule (round-12 proven, ~990 TF) ----------
__global__ __launch_bounds__(512, 2) void k_gemm(const unsigned short* __restrict__ A,
                                                 const unsigned short* __restrict__ Bw,
                                                 void* __restrict__ Cc,
                                                 int Nc, int Kd, int nxl, int bf16out) {
  __shared__ unsigned short shA[2][256 * 64];
  __shared__ unsigned short shB[2][256 * 64];
  const int tid = threadIdx.x, w = tid >> 6, l = tid & 63;
  const int xcd = blockIdx.x & 7, loc = blockIdx.x >> 3;
  const int m0 = ((xcd >> 1) * 4 + loc / nxl) * 256;
  const int n0 = ((xcd & 1) * nxl + loc % nxl) * 256;

  const int srow = l >> 3;                      // 0..7
  const int sw_colb = (((l & 7) ^ srow) << 4);  // inverse-swizzled source col (bytes)
  const int wrow = w * 8;
  const int NT = Kd >> 6;

#define STG_A(buf, t, r)                                                                     \
  {                                                                                          \
    const char* src_ = (const char*)A +                                                      \
        ((size_t)(m0 + (r) * 64 + wrow + srow) * Kd + ((size_t)(t) << 6)) * 2 + sw_colb;     \
    __builtin_amdgcn_global_load_lds(                                                        \
        (__attribute__((address_space(1))) void*)src_,                                       \
        (__attribute__((address_space(3))) void*)((char*)&shA[buf][0] + (r) * 8192 + w * 1024), \
        16, 0, 0);                                                                           \
  }
#define STG_B(buf, t, r)                                                                     \
  {                                                                                          \
    const char* src_ = (const char*)Bw +                                                     \
        ((size_t)(n0 + (r) * 64 + wrow + srow) * Kd + ((size_t)(t) << 6)) * 2 + sw_colb;     \
    __builtin_amdgcn_global_load_lds(                                                        \
        (__attribute__((address_space(1))) void*)src_,                                       \
        (__attribute__((address_space(3))) void*)((char*)&shB[buf][0] + (r) * 8192 + w * 1024), \
        16, 0, 0);                                                                           \
  }

  const int wm = w >> 2, wn = w & 3;  // 2M x 4N wave grid
  const int lr = l & 15, lg = l >> 4;
  const int rswz = (lr & 7) << 4;
  const int c0x = (lg * 16) ^ rswz;        // kk0 column (swizzled)
  const int c1x = (64 + lg * 16) ^ rswz;   // kk1 column (swizzled)
  f32x4 acc[8][4] = {};

  // prologue: fully stage tile 0
#pragma unroll
  for (int r = 0; r < 4; ++r) { STG_A(0, 0, r); STG_B(0, 0, r); }
  asm volatile("s_waitcnt vmcnt(0)" ::: "memory");
  __builtin_amdgcn_s_barrier();

  for (int t = 0; t < NT; ++t) {
    const int buf = t & 1;
    const bool pf = (t + 1 < NT);
    const char* sa = (const char*)&shA[buf][0];
    const char* sb = (const char*)&shB[buf][0];
    s16x8 af[4], bf0[4], bf1[4];

    // ---- phase 0: kk0, A-even quarter (mi 0-3) + B kk0 ----
#pragma unroll
    for (int mi = 0; mi < 4; ++mi)
      af[mi] = *(const s16x8*)(sa + (wm * 128 + mi * 16 + lr) * 128 + c0x);
#pragma unroll
    for (int ni = 0; ni < 4; ++ni)
      bf0[ni] = *(const s16x8*)(sb + (wn * 64 + ni * 16 + lr) * 128 + c0x);
    asm volatile("s_waitcnt vmcnt(0)" ::: "memory");
    if (pf) { STG_A(buf ^ 1, t + 1, 0); STG_A(buf ^ 1, t + 1, 2); }
    __builtin_amdgcn_s_barrier();
    asm volatile("s_waitcnt lgkmcnt(0)" ::: "memory");
    __builtin_amdgcn_s_setprio(1);
#pragma unroll
    for (int mi = 0; mi < 4; ++mi)
#pragma unroll
      for (int ni = 0; ni < 4; ++ni)
        acc[mi][ni] = __builtin_amdgcn_mfma_f32_16x16x32_bf16(af[mi], bf0[ni], acc[mi][ni], 0, 0, 0);
    __builtin_amdgcn_s_setprio(0);
    __builtin_amdgcn_s_barrier();

    // ---- phase 1: kk0, A-odd quarter (mi 4-7), B regs reused ----
#pragma unroll
    for (int mi = 0; mi < 4; ++mi)
      af[mi] = *(const s16x8*)(sa + (wm * 128 + (4 + mi) * 16 + lr) * 128 + c0x);
    if (pf) { STG_B(buf ^ 1, t + 1, 0); STG_B(buf ^ 1, t + 1, 1); }
    __builtin_amdgcn_s_barrier();
    asm volatile("s_waitcnt lgkmcnt(0)" ::: "memory");
    __builtin_amdgcn_s_setprio(1);
#pragma unroll
    for (int mi = 0; mi < 4; ++mi)
#pragma unroll
      for (int ni = 0; ni < 4; ++ni)
        acc[4 + mi][ni] = __builtin_amdgcn_mfma_f32_16x16x32_bf16(af[mi], bf0[ni], acc[4 + mi][ni], 0, 0, 0);
    __builtin_amdgcn_s_setprio(0);
    __builtin_amdgcn_s_barrier();

    // ---- phase 2: kk1, A-even + B kk1 ----
#pragma unroll
    for (int mi = 0; mi < 4; ++mi)
      af[mi] = *(const s16x8*)(sa + (wm * 128 + mi * 16 + lr) * 128 + c1x);
#pragma unroll
    for (int ni = 0; ni < 4; ++ni)
      bf1[ni] = *(const s16x8*)(sb + (wn * 64 + ni * 16 + lr) * 128 + c1x);
    if (pf) { STG_B(buf ^ 1, t + 1, 2); STG_B(buf ^ 1, t + 1, 3); }
    __builtin_amdgcn_s_barrier();
    asm volatile("s_waitcnt lgkmcnt(0)" ::: "memory");
    __builtin_amdgcn_s_setprio(1);
#pragma unroll
    for (int mi = 0; mi < 4; ++mi)
#pragma unroll
      for (int ni = 0; ni < 4; ++ni)
        acc[mi][ni] = __builtin_amdgcn_mfma_f32_16x16x32_bf16(af[mi], bf1[ni], acc[mi][ni], 0, 0, 0);
    __builtin_amdgcn_s_setprio(0);
    __builtin_amdgcn_s_barrier();

    // ---- phase 3: kk1, A-odd; stage A q1,q3 LAST ----
#pragma unroll
    for (int mi = 0; mi < 4; ++mi)
      af[mi] = *(const s16x8*)(sa + (wm * 128 + (4 + mi) * 16 + lr) * 128 + c1x);
    if (pf) { STG_A(buf ^ 1, t + 1, 1); STG_A(buf ^ 1, t + 1, 3); }
    __builtin_amdgcn_s_barrier();
    asm volatile("s_waitcnt lgkmcnt(0)" ::: "memory");
    __builtin_amdgcn_s_setprio(1);
#pragma unroll
    for (int mi = 0; mi < 4; ++mi)
#pragma unroll
      for (int ni = 0; ni < 4; ++ni)
        acc[4 + mi][ni] = __builtin_amdgcn_mfma_f32_16x16x32_bf16(af[mi], bf1[ni], acc[4 + mi][ni], 0, 0, 0);
    __builtin_amdgcn_s_setprio(0);
    if (pf) {
      asm volatile("s_waitcnt vmcnt(2)" ::: "memory");
    } else {
      asm volatile("s_waitcnt vmcnt(0)" ::: "memory");
    }
    __builtin_amdgcn_s_barrier();
  }
#undef STG_A
#undef STG_B

  if (bf16out) {
    unsigned short* Co = (unsigned short*)Cc;
#pragma unroll
    for (int mi = 0; mi < 8; ++mi)
#pragma unroll
      for (int ni = 0; ni < 4; ++ni) {
        size_t base = (size_t)(m0 + wm * 128 + mi * 16 + lg * 4) * Nc + (n0 + wn * 64 + ni * 16 + lr);
#pragma unroll
        for (int i = 0; i < 4; ++i)
          Co[base + (size_t)i * Nc] = f2bf(acc[mi][ni][i]);
      }
  } else {
    float* Co = (float*)Cc;
#pragma unroll
    for (int mi = 0; mi < 8; ++mi)
#pragma unroll
      for (int ni = 0; ni < 4; ++ni) {
        size_t base = (size_t)(m0 + wm * 128 + mi * 16 + lg * 4) * Nc + (n0 + wn * 64 + ni * 16 + lr);
#pragma unroll
        for (int i = 0; i < 4; ++i)
          Co[base + (size_t)i * Nc] = acc[mi][ni][i];
      }
  }
}

// ---------- GEMM3: 256x160 tile -> 16m x 16n = 256 blocks = exactly 1/CU (round-15 proven) ----------
__global__ __launch_bounds__(512, 2) void k_gemm3(const unsigned short* __restrict__ A,
                                                  const unsigned short* __restrict__ Bw,
                                                  float* __restrict__ Cc) {
  const int Nc = 2560, Kd = 2048;
  __shared__ unsigned short shA[2][256 * 64];
  __shared__ unsigned short shB[2][160 * 64];
  const int tid = threadIdx.x, w = tid >> 6, l = tid & 63;
  const int xcd = blockIdx.x & 7, loc = blockIdx.x >> 3;  // loc 0..31
  const int m0 = (xcd * 2 + (loc >> 4)) * 256;            // 16 m-tiles, 2 per XCD
  const int n0 = (loc & 15) * 160;                        // 16 n-tiles

  const int srow = l >> 3;                      // 0..7
  const int sw_colb = (((l & 7) ^ srow) << 4);  // inverse-swizzled source col (bytes)
  const int wrow = w * 8;
  const int NT = Kd >> 6;  // 32

  // per-wave issue count: A x4 + B x2 + (w<4 ? B x1 : 0) = 7 or 6
#define GSTAGE3(buf, t)                                                                     \
  {                                                                                         \
    const size_t kt = (size_t)(t) << 6;                                                     \
    _Pragma("unroll") for (int r = 0; r < 4; ++r) {                                         \
      const char* srcA = (const char*)A +                                                   \
          ((size_t)(m0 + r * 64 + wrow + srow) * Kd + kt) * 2 + sw_colb;                    \
      __builtin_amdgcn_global_load_lds(                                                     \
          (__attribute__((address_space(1))) void*)srcA,                                    \
          (__attribute__((address_space(3))) void*)((char*)&shA[buf][0] + r * 8192 + w * 1024), \
          16, 0, 0);                                                                        \
    }                                                                                       \
    _Pragma("unroll") for (int r = 0; r < 2; ++r) {                                         \
      const char* srcB = (const char*)Bw +                                                  \
          ((size_t)(n0 + r * 64 + wrow + srow) * Kd + kt) * 2 + sw_colb;                    \
      __builtin_amdgcn_global_load_lds(                                                     \
          (__attribute__((address_space(1))) void*)srcB,                                    \
          (__attribute__((address_space(3))) void*)((char*)&shB[buf][0] + r * 8192 + w * 1024), \
          16, 0, 0);                                                                        \
    }                                                                                       \
    if (w < 4) {                                                                            \
      const char* srcB = (const char*)Bw +                                                  \
          ((size_t)(n0 + 128 + wrow + srow) * Kd + kt) * 2 + sw_colb;                       \
      __builtin_amdgcn_global_load_lds(                                                     \
          (__attribute__((address_space(1))) void*)srcB,                                    \
          (__attribute__((address_space(3))) void*)((char*)&shB[buf][0] + 16384 + w * 1024), \
          16, 0, 0);                                                                        \
    }                                                                                       \
  }

  const int wm = w >> 1, wn = w & 1;  // 4M x 2N wave grid, per-wave 64x80
  const int lr = l & 15, lg = l >> 4;
  const int rswz = (lr & 7) << 4;
  f32x4 acc[4][5] = {};

  GSTAGE3(0, 0);

  for (int t = 0; t < NT; ++t) {
    const int buf = t & 1;
    if (t + 1 < NT) {
      GSTAGE3(buf ^ 1, t + 1);
      if (w < 4) {
        asm volatile("s_waitcnt vmcnt(7)" ::: "memory");
      } else {
        asm volatile("s_waitcnt vmcnt(6)" ::: "memory");
      }
    } else {
      asm volatile("s_waitcnt vmcnt(0)" ::: "memory");
    }
    __builtin_amdgcn_s_barrier();

    const char* sa = (const char*)&shA[buf][0];
    const char* sb = (const char*)&shB[buf][0];
#pragma unroll
    for (int kk = 0; kk < 2; ++kk) {
      const int cbx = (kk * 64 + lg * 16) ^ rswz;
      s16x8 af[4], bfr[5];
#pragma unroll
      for (int mi = 0; mi < 4; ++mi)
        af[mi] = *(const s16x8*)(sa + (wm * 64 + mi * 16 + lr) * 128 + cbx);
#pragma unroll
      for (int ni = 0; ni < 5; ++ni)
        bfr[ni] = *(const s16x8*)(sb + (wn * 80 + ni * 16 + lr) * 128 + cbx);
      __builtin_amdgcn_s_setprio(1);
#pragma unroll
      for (int mi = 0; mi < 4; ++mi)
#pragma unroll
        for (int ni = 0; ni < 5; ++ni)
          acc[mi][ni] = __builtin_amdgcn_mfma_f32_16x16x32_bf16(af[mi], bfr[ni], acc[mi][ni], 0, 0, 0);
      __builtin_amdgcn_s_setprio(0);
    }
    __builtin_amdgcn_s_barrier();
  }
#undef GSTAGE3

#pragma unroll
  for (int mi = 0; mi < 4; ++mi)
#pragma unroll
    for (int ni = 0; ni < 5; ++ni) {
      size_t base = (size_t)(m0 + wm * 64 + mi * 16 + lg * 4) * Nc + (n0 + wn * 80 + ni * 16 + lr);
#pragma unroll
      for (int i = 0; i < 4; ++i)
        Cc[base + (size_t)i * Nc] = acc[mi][ni][i];
    }
}

// ---------- fused RMSNorm+RoPE (blocks 0..4095) and V-transpose (blocks 4096..5119) ----------
__global__ __launch_bounds__(256) void k_post(const unsigned short* __restrict__ Y,
                                              const float* __restrict__ qsc,
                                              const float* __restrict__ ksc,
                                              const int* __restrict__ pos,
                                              unsigned short* __restrict__ Q,
                                              unsigned short* __restrict__ Kb,
                                              unsigned short* __restrict__ VT) {
  __shared__ float s_sin[128], s_cos[128];
  __shared__ unsigned short ttile[64][65];
  const int tid = threadIdx.x;
  if (blockIdx.x < 4096) {
    // ---- RMSNorm + RoPE ----
    const int bt = blockIdx.x;
    const int b = bt >> 11, t = bt & (TB - 1);
    float p = (float)pos[bt];
    if (tid < 128) {
      float fr = (float)tid * (1.0f / 128.0f);
      float inv_ts = __expf(fr * -9.210340371976184f);  // 10000^-fr
      float ang = p * inv_ts;
      float sv, cv;
      sincosf(ang, &sv, &cv);
      s_sin[tid] = sv;
      s_cos[tid] = cv;
    }
    __syncthreads();
    const int w = tid >> 6, l = tid & 63;
    const int jj0 = (l & 31) * 4;
    for (int sidx = w; sidx < 12; sidx += 4) {  // 0..7 q heads, 8..11 k heads
      const unsigned short* src = Y + (size_t)bt * 4096 + sidx * 256;
      u16x4 vb = *(const u16x4*)&src[l * 4];
      float v[4];
#pragma unroll
      for (int j = 0; j < 4; ++j) v[j] = bf2f(vb[j]);
      float ss = v[0] * v[0] + v[1] * v[1] + v[2] * v[2] + v[3] * v[3];
#pragma unroll
      for (int d = 1; d < 64; d <<= 1) ss += __shfl_xor(ss, d);
      float rs = rsqrtf(ss * (1.0f / 256.0f) + 1e-6f);
      const float* scp = (sidx < 8) ? qsc : ksc;
      float nv[4], res[4];
#pragma unroll
      for (int j = 0; j < 4; ++j) nv[j] = v[j] * rs * (1.0f + scp[l * 4 + j]);
#pragma unroll
      for (int j = 0; j < 4; ++j) {
        float o = __shfl_xor(nv[j], 32);
        float sn = s_sin[jj0 + j], cs = s_cos[jj0 + j];
        res[j] = (l < 32) ? (nv[j] * cs - o * sn) : (nv[j] * cs + o * sn);
      }
      float qs = (sidx < 8) ? 0.0625f : 1.0f;  // H^-0.5 = 1/16 folded into q
      u16x4 ob;
#pragma unroll
      for (int j = 0; j < 4; ++j) ob[j] = f2bf(res[j] * qs);
      if (sidx < 8) {
        size_t di = ((size_t)(b * NQ + sidx) * TB + t) * HDIM + l * 4;
        *(u16x4*)&Q[di] = ob;
      } else {
        size_t di = ((size_t)(b * NKV + (sidx - 8)) * TB + t) * HDIM + l * 4;
        *(u16x4*)&Kb[di] = ob;
      }
    }
  } else {
    // ---- V transpose: Y v-channels -> VT[B][NKV][H][T] ----
    const int zz = blockIdx.x - 4096;  // 1024 blocks: (t0 32) x (h0 4) x (bn 8)
    const int t0 = (zz & 31) * 64;
    const int h0 = ((zz >> 5) & 3) * 64;
    const int z = zz >> 7;  // b*4+kh
    const int bq = z >> 2, kh = z & 3;
#pragma unroll
    for (int rep = 0; rep < 16; ++rep) {
      int idx = rep * 256 + tid;
      int tr = idx >> 6, hc = idx & 63;
      ttile[tr][hc] = Y[(size_t)(bq * TB + t0 + tr) * 4096 + 3072 + kh * 256 + h0 + hc];
    }
    __syncthreads();
#pragma unroll
    for (int rep = 0; rep < 16; ++rep) {
      int idx = rep * 256 + tid;
      int hr = idx >> 6, tc = idx & 63;
      VT[((size_t)z * 256 + h0 + hr) * TB + t0 + tc] = ttile[tc][hr];
    }
  }
}

// ---------- flash attention: 8 waves / 128 q-rows share K/V tiles; counted-vmcnt pipeline ----------
__global__ __launch_bounds__(512, 2) void k_attn(const unsigned short* __restrict__ Q,
                                                 const unsigned short* __restrict__ Kb,
                                                 const unsigned short* __restrict__ VT,
                                                 unsigned short* __restrict__ ENC) {
  __shared__ unsigned short shK[2][32 * 256];  // [s-row][h], 512B rows, XOR-swizzled
  __shared__ unsigned short shV[2][256 * 32];  // [h-row][s], 64B rows
  __shared__ unsigned short Pb[8][16 * 40];    // 80B rows
  const int tid = threadIdx.x, w = tid >> 6, l = tid & 63;
  const int bn = blockIdx.y;
  const int b = bn >> 3, n = bn & 7, kh = n >> 1;
  const int t0b = blockIdx.x * 128;
  const int t0 = t0b + w * 16;  // 8 waves cover 128 q-rows
  const int lr = l & 15, lg = l >> 4;
  const unsigned short* qp = Q + ((size_t)bn * TB + t0) * HDIM;
  const char* kbase = (const char*)(Kb + ((size_t)(b * NKV + kh) * TB) * HDIM);
  const char* vbase = (const char*)(VT + ((size_t)(b * NKV + kh) * HDIM) * TB);

  s16x8 aq[8];
#pragma unroll
  for (int kk = 0; kk < 8; ++kk)
    aq[kk] = *(const s16x8*)&qp[lr * HDIM + kk * 32 + lg * 8];

  f32x4 o[16] = {};
  float mrow[4], lsum[4];  // per-lane lsum partials; reduced at epilogue
#pragma unroll
  for (int i = 0; i < 4; ++i) { mrow[i] = -__builtin_inff(); lsum[i] = 0.f; }

  int lo = t0b - (WIN - 1);
  if (lo < 0) lo = 0;
  lo &= ~31;
  const int nsteps = (t0b + 128 - lo) / 32;

  // 512 threads stage 32x256 K (2 issues/lane) + 256x32 V (2 issues/lane).
  // dest = i_*8192 + tid*16 (LINEAR, per-thread unique); K source row-swizzled (involution).
  // mapping check: shK row = i_*16 + tid/32 = i_*16 + 2w + (l>>5) == source row; col (l&31)*16.
  //                shV row = i_*128 + tid/4 = i_*128 + 16w + (l>>2) == source row; col (tid&3)*16.
  const int k_row = (w << 1) + (l >> 5);   // + i_*16
  const int k_colb = (l & 31) * 16;
  const int v_row = (w << 4) + (l >> 2);   // + i_*128
  const int v_colb = (l & 3) * 16;
#define STAGE(buf, s0)                                                                       \
  {                                                                                          \
    _Pragma("unroll") for (int i_ = 0; i_ < 2; ++i_) {                                       \
      int row = i_ * 16 + k_row;                                                             \
      int scol = k_colb ^ ((row & 7) << 4);                                                  \
      const char* src = kbase + (size_t)((s0) + row) * 512 + scol;                           \
      __builtin_amdgcn_global_load_lds(                                                      \
          (__attribute__((address_space(1))) void*)src,                                      \
          (__attribute__((address_space(3))) void*)((char*)&shK[buf][0] + i_ * 8192 + tid * 16), \
          16, 0, 0);                                                                         \
    }                                                                                        \
    _Pragma("unroll") for (int i_ = 0; i_ < 2; ++i_) {                                       \
      int row = i_ * 128 + v_row;                                                            \
      const char* src = vbase + (size_t)row * (TB * 2) + (size_t)(s0) * 2 + v_colb;          \
      __builtin_amdgcn_global_load_lds(                                                      \
          (__attribute__((address_space(1))) void*)src,                                      \
          (__attribute__((address_space(3))) void*)((char*)&shV[buf][0] + i_ * 8192 + tid * 16), \
          16, 0, 0);                                                                         \
    }                                                                                        \
  }

  STAGE(0, lo);

  for (int step = 0; step < nsteps; ++step) {
    const int s0 = lo + step * 32;
    const int buf = step & 1;
    if (step + 1 < nsteps) {
      STAGE(buf ^ 1, s0 + 32);
      asm volatile("s_waitcnt vmcnt(4)" ::: "memory");  // tile `step` resident; next in flight
    } else {
      asm volatile("s_waitcnt vmcnt(0)" ::: "memory");
    }
    __builtin_amdgcn_s_barrier();

    const bool active = (s0 <= t0 + 15) && (s0 + 31 >= t0 - (WIN - 1));
    if (active) {
      // QK^T from LDS (swizzled read)
      f32x4 sacc[2] = {};
      const char* kt = (const char*)&shK[buf][0];
      const int swz = (lr & 7) << 4;
#pragma unroll
      for (int cb = 0; cb < 2; ++cb) {
        const int rb = (cb * 16 + lr) * 512;
        s16x8 bk[8];
#pragma unroll
        for (int kk = 0; kk < 8; ++kk)
          bk[kk] = *(const s16x8*)(kt + rb + ((kk * 64 + lg * 16) ^ swz));
        __builtin_amdgcn_s_setprio(1);
#pragma unroll
        for (int kk = 0; kk < 8; ++kk)
          sacc[cb] = __builtin_amdgcn_mfma_f32_16x16x32_bf16(aq[kk], bk[kk], sacc[cb], 0, 0, 0);
        __builtin_amdgcn_s_setprio(0);
      }
      // mask (skipped for interior steps: wave-uniform branch)
      float svA_[4], svB_[4];
      const bool nomask = (s0 + 31 <= t0) && (s0 >= t0 - (WIN - 16));
      if (nomask) {
#pragma unroll
        for (int i = 0; i < 4; ++i) { svA_[i] = sacc[0][i]; svB_[i] = sacc[1][i]; }
      } else {
#pragma unroll
        for (int i = 0; i < 4; ++i) {
          int trow = t0 + lg * 4 + i;
          int sA = s0 + lr, sB = s0 + 16 + lr;
          svA_[i] = ((sA <= trow) && (trow - sA < WIN)) ? sacc[0][i] : KMASK;
          svB_[i] = ((sB <= trow) && (trow - sB < WIN)) ? sacc[1][i] : KMASK;
        }
      }
      // defer-rescale (T13)
      bool ok = true;
#pragma unroll
      for (int i = 0; i < 4; ++i)
        ok = ok && (svA_[i] <= mrow[i] + 8.f) && (svB_[i] <= mrow[i] + 8.f);
      if (!__all(ok)) {
        float r_[4];
#pragma unroll
        for (int i = 0; i < 4; ++i) {
          float mx = fmaxf(svA_[i], svB_[i]);
#pragma unroll
          for (int d = 1; d < 16; d <<= 1) mx = fmaxf(mx, __shfl_xor(mx, d));
          float mnew = fmaxf(mrow[i], mx);
          r_[i] = __expf(mrow[i] - mnew);
          lsum[i] *= r_[i];
          mrow[i] = mnew;
        }
#pragma unroll
        for (int hb = 0; hb < 16; ++hb)
#pragma unroll
          for (int i = 0; i < 4; ++i) o[hb][i] *= r_[i];
      }
      // P = exp(S - m); per-lane lsum accumulation
#pragma unroll
      for (int i = 0; i < 4; ++i) {
        float pa = __expf(svA_[i] - mrow[i]);
        float pb = __expf(svB_[i] - mrow[i]);
        lsum[i] += pa + pb;
        int row = lg * 4 + i;
        Pb[w][row * 40 + lr] = f2bf(pa);
        Pb[w][row * 40 + 16 + lr] = f2bf(pb);
      }
      asm volatile("s_waitcnt lgkmcnt(0)" ::: "memory");
      s16x8 pfrag = *(const s16x8*)&Pb[w][lr * 40 + lg * 8];
      // PV from LDS V-tile
      const char* vt = (const char*)&shV[buf][0];
      s16x8 vb[16];
#pragma unroll
      for (int hb = 0; hb < 16; ++hb)
        vb[hb] = *(const s16x8*)(vt + (hb * 16 + lr) * 64 + lg * 16);
      __builtin_amdgcn_s_setprio(1);
#pragma unroll
      for (int hb = 0; hb < 16; ++hb)
        o[hb] = __builtin_amdgcn_mfma_f32_16x16x32_bf16(pfrag, vb[hb], o[hb], 0, 0, 0);
      __builtin_amdgcn_s_setprio(0);
    }
    __builtin_amdgcn_s_barrier();  // protect dbuf overwrite by next step's STAGE
  }
#undef STAGE

  // epilogue: reduce per-lane lsum across the row's 16 lanes
#pragma unroll
  for (int i = 0; i < 4; ++i) {
    float s = lsum[i];
#pragma unroll
    for (int d = 1; d < 16; d <<= 1) s += __shfl_xor(s, d);
    lsum[i] = s;
  }
#pragma unroll
  for (int i = 0; i < 4; ++i) {
    int trow = t0 + lg * 4 + i;
    float inv = 1.0f / lsum[i];
    size_t rb = (size_t)(b * TB + trow) * 2048 + n * HDIM;
#pragma unroll
    for (int hb = 0; hb < 16; ++hb)
      ENC[rb + hb * 16 + lr] = f2bf(o[hb][i] * inv);
  }
}

extern "C" void kernel_launch(void* const* d_in, const int* in_sizes, int n_in,
                              void* d_out, int out_size, void* d_ws, size_t ws_size,
                              hipStream_t stream) {
  (void)in_sizes; (void)n_in; (void)out_size; (void)ws_size;
  const float* x = (const float*)d_in[0];
  const float* q_w = (const float*)d_in[1];
  const float* kv_w = (const float*)d_in[2];
  const float* qsc = (const float*)d_in[3];
  const float* ksc = (const float*)d_in[4];
  const float* out_w = (const float*)d_in[5];
  const int* pos = (const int*)d_in[6];
  float* out = (float*)d_out;

  char* ws = (char*)d_ws;
  unsigned short* W1 = (unsigned short*)(ws);              // 4096x2560 bf16 (20.97 MB)
  unsigned short* W3 = (unsigned short*)(ws + 20971520);   // 2560x2048 bf16 (10.49 MB)
  unsigned short* XB = (unsigned short*)(ws + 31457280);   // 4096x2560 bf16 (20.97 MB)
  unsigned short* Y = (unsigned short*)(ws + 52428800);    // 4096x4096 bf16 (33.5 MB)
  unsigned short* KB = (unsigned short*)(ws + 119537664);  // 2x4x2048x256 bf16 (8.39 MB)
  unsigned short* VT = (unsigned short*)(ws + 127926272);  // 2x4x256x2048 bf16 (8.39 MB)
  unsigned short* Qb = XB;                                 // reuse XB after GEMM1
  unsigned short* ENC = (unsigned short*)(ws + 90000000);  // after Y region (distinct)

  // fused prep: W1 pack (10240) + W3 transpose (5120) + x cvt (10240)
  k_prep<<<dim3(25600), 256, 0, stream>>>(q_w, kv_w, out_w, x, W1, W3, XB);
  // GEMM1: M=4096 (16 m-tiles), N=4096 (16 n-tiles) -> 256 blocks, XCD region 4m x 8n
  k_gemm<<<dim3(256), 512, 0, stream>>>(XB, W1, Y, 4096, DIM, 8, 1);
  // fused normrope (4096 blocks) + vtrans (1024 blocks)
  k_post<<<dim3(5120), 256, 0, stream>>>(Y, qsc, ksc, pos, Qb, KB, VT);
  // attn: 16 column groups x 16 (b,n) = 256 blocks, 8 waves each
  k_attn<<<dim3(16, 16), 512, 0, stream>>>(Qb, KB, VT, ENC);
  // GEMM3: 256x160 tile -> 16 x 16 = 256 blocks, exactly 1/CU
  k_gemm3<<<dim3(256), 512, 0, stream>>>(ENC, W3, out);
}

// Round 19
// 239.875 us; speedup vs baseline: 1.0308x; 1.0308x over previous
//
#include <hip/hip_runtime.h>
#include <cstdint>

#define TB 2048     // T
#define DIM 2560    // D
#define NQ 8
#define NKV 4
#define HDIM 256
#define WIN 1024
#define KMASK -2.3819763e+38f

using f32x4 = __attribute__((ext_vector_type(4))) float;
using s16x8 = __attribute__((ext_vector_type(8))) short;
using u16x4 = __attribute__((ext_vector_type(4))) unsigned short;

__device__ __forceinline__ unsigned short f2bf(float f) {
  uint32_t x = __builtin_bit_cast(uint32_t, f);
  x += 0x7FFFu + ((x >> 16) & 1u);
  return (unsigned short)(x >> 16);
}

__device__ __forceinline__ float bf2f(unsigned short u) {
  uint32_t x = (uint32_t)u << 16;
  return __builtin_bit_cast(float, x);
}

// ---------- fused prep: W1 pack (blocks 0..10239), W3 transpose (10240..15359),
// ---------- x f32->bf16 (15360..25599) ----------
__global__ __launch_bounds__(256) void k_prep(const float* __restrict__ q_w,
                                              const float* __restrict__ kv_w,
                                              const float* __restrict__ out_w,
                                              const float* __restrict__ x,
                                              unsigned short* __restrict__ W1,
                                              unsigned short* __restrict__ W3,
                                              unsigned short* __restrict__ XB) {
  __shared__ float tile[32][33];
  const int bi = blockIdx.x;
  const int tid = threadIdx.x;
  if (bi < 10240) {
    // ---- pack W1: head hd of (DIM x HDIM) f32 -> W1[c][d] bf16 ----
    const int hd = bi / 640;
    const int rem = bi % 640;
    const int r0 = (rem / 8) * 32, c0 = (rem % 8) * 32;
    const float* src = (hd < 8) ? (q_w + (size_t)hd * DIM * HDIM)
                                : (kv_w + (size_t)(hd - 8) * DIM * HDIM);
    unsigned short* dst = W1 + (size_t)hd * HDIM * DIM;
    const int tx = tid & 31, ty = tid >> 5;
#pragma unroll
    for (int i = 0; i < 32; i += 8)
      tile[ty + i][tx] = src[(size_t)(r0 + ty + i) * HDIM + c0 + tx];
    __syncthreads();
#pragma unroll
    for (int i = 0; i < 32; i += 8)
      dst[(size_t)(c0 + ty + i) * DIM + r0 + tx] = f2bf(tile[tx][ty + i]);
  } else if (bi < 15360) {
    // ---- transpose out_w f32 (2048 x 2560) -> W3 bf16 (2560 x 2048) ----
    const int j = bi - 10240;
    const int c0 = (j % 80) * 32, r0 = (j / 80) * 32;
    const int tx = tid & 31, ty = tid >> 5;
#pragma unroll
    for (int i = 0; i < 32; i += 8)
      tile[ty + i][tx] = out_w[(size_t)(r0 + ty + i) * DIM + c0 + tx];
    __syncthreads();
#pragma unroll
    for (int i = 0; i < 32; i += 8)
      W3[(size_t)(c0 + ty + i) * 2048 + r0 + tx] = f2bf(tile[tx][ty + i]);
  } else {
    // ---- x f32 -> bf16, 4 elems/thread ----
    const int j = bi - 15360;
    int i = j * 256 + tid;
    f32x4 v = *(const f32x4*)&x[(size_t)i * 4];
    u16x4 o;
#pragma unroll
    for (int k = 0; k < 4; ++k) o[k] = f2bf(v[k]);
    *(u16x4*)&XB[(size_t)i * 4] = o;
  }
}

// ---------- 256x256 tile bf16 GEMM, 4-phase schedule (round-12 proven, ~990 TF) ----------
__global__ __launch_bounds__(512, 2) void k_gemm(const unsigned short* __restrict__ A,
                                                 const unsigned short* __restrict__ Bw,
                                                 void* __restrict__ Cc,
                                                 int Nc, int Kd, int nxl, int bf16out) {
  __shared__ unsigned short shA[2][256 * 64];
  __shared__ unsigned short shB[2][256 * 64];
  const int tid = threadIdx.x, w = tid >> 6, l = tid & 63;
  const int xcd = blockIdx.x & 7, loc = blockIdx.x >> 3;
  const int m0 = ((xcd >> 1) * 4 + loc / nxl) * 256;
  const int n0 = ((xcd & 1) * nxl + loc % nxl) * 256;

  const int srow = l >> 3;                      // 0..7
  const int sw_colb = (((l & 7) ^ srow) << 4);  // inverse-swizzled source col (bytes)
  const int wrow = w * 8;
  const int NT = Kd >> 6;

#define STG_A(buf, t, r)                                                                     \
  {                                                                                          \
    const char* src_ = (const char*)A +                                                      \
        ((size_t)(m0 + (r) * 64 + wrow + srow) * Kd + ((size_t)(t) << 6)) * 2 + sw_colb;     \
    __builtin_amdgcn_global_load_lds(                                                        \
        (__attribute__((address_space(1))) void*)src_,                                       \
        (__attribute__((address_space(3))) void*)((char*)&shA[buf][0] + (r) * 8192 + w * 1024), \
        16, 0, 0);                                                                           \
  }
#define STG_B(buf, t, r)                                                                     \
  {                                                                                          \
    const char* src_ = (const char*)Bw +                                                     \
        ((size_t)(n0 + (r) * 64 + wrow + srow) * Kd + ((size_t)(t) << 6)) * 2 + sw_colb;     \
    __builtin_amdgcn_global_load_lds(                                                        \
        (__attribute__((address_space(1))) void*)src_,                                       \
        (__attribute__((address_space(3))) void*)((char*)&shB[buf][0] + (r) * 8192 + w * 1024), \
        16, 0, 0);                                                                           \
  }

  const int wm = w >> 2, wn = w & 3;  // 2M x 4N wave grid
  const int lr = l & 15, lg = l >> 4;
  const int rswz = (lr & 7) << 4;
  const int c0x = (lg * 16) ^ rswz;        // kk0 column (swizzled)
  const int c1x = (64 + lg * 16) ^ rswz;   // kk1 column (swizzled)
  f32x4 acc[8][4] = {};

  // prologue: fully stage tile 0
#pragma unroll
  for (int r = 0; r < 4; ++r) { STG_A(0, 0, r); STG_B(0, 0, r); }
  asm volatile("s_waitcnt vmcnt(0)" ::: "memory");
  __builtin_amdgcn_s_barrier();

  for (int t = 0; t < NT; ++t) {
    const int buf = t & 1;
    const bool pf = (t + 1 < NT);
    const char* sa = (const char*)&shA[buf][0];
    const char* sb = (const char*)&shB[buf][0];
    s16x8 af[4], bf0[4], bf1[4];

    // ---- phase 0: kk0, A-even quarter (mi 0-3) + B kk0 ----
#pragma unroll
    for (int mi = 0; mi < 4; ++mi)
      af[mi] = *(const s16x8*)(sa + (wm * 128 + mi * 16 + lr) * 128 + c0x);
#pragma unroll
    for (int ni = 0; ni < 4; ++ni)
      bf0[ni] = *(const s16x8*)(sb + (wn * 64 + ni * 16 + lr) * 128 + c0x);
    asm volatile("s_waitcnt vmcnt(0)" ::: "memory");
    if (pf) { STG_A(buf ^ 1, t + 1, 0); STG_A(buf ^ 1, t + 1, 2); }
    __builtin_amdgcn_s_barrier();
    asm volatile("s_waitcnt lgkmcnt(0)" ::: "memory");
    __builtin_amdgcn_s_setprio(1);
#pragma unroll
    for (int mi = 0; mi < 4; ++mi)
#pragma unroll
      for (int ni = 0; ni < 4; ++ni)
        acc[mi][ni] = __builtin_amdgcn_mfma_f32_16x16x32_bf16(af[mi], bf0[ni], acc[mi][ni], 0, 0, 0);
    __builtin_amdgcn_s_setprio(0);
    __builtin_amdgcn_s_barrier();

    // ---- phase 1: kk0, A-odd quarter (mi 4-7), B regs reused ----
#pragma unroll
    for (int mi = 0; mi < 4; ++mi)
      af[mi] = *(const s16x8*)(sa + (wm * 128 + (4 + mi) * 16 + lr) * 128 + c0x);
    if (pf) { STG_B(buf ^ 1, t + 1, 0); STG_B(buf ^ 1, t + 1, 1); }
    __builtin_amdgcn_s_barrier();
    asm volatile("s_waitcnt lgkmcnt(0)" ::: "memory");
    __builtin_amdgcn_s_setprio(1);
#pragma unroll
    for (int mi = 0; mi < 4; ++mi)
#pragma unroll
      for (int ni = 0; ni < 4; ++ni)
        acc[4 + mi][ni] = __builtin_amdgcn_mfma_f32_16x16x32_bf16(af[mi], bf0[ni], acc[4 + mi][ni], 0, 0, 0);
    __builtin_amdgcn_s_setprio(0);
    __builtin_amdgcn_s_barrier();

    // ---- phase 2: kk1, A-even + B kk1 ----
#pragma unroll
    for (int mi = 0; mi < 4; ++mi)
      af[mi] = *(const s16x8*)(sa + (wm * 128 + mi * 16 + lr) * 128 + c1x);
#pragma unroll
    for (int ni = 0; ni < 4; ++ni)
      bf1[ni] = *(const s16x8*)(sb + (wn * 64 + ni * 16 + lr) * 128 + c1x);
    if (pf) { STG_B(buf ^ 1, t + 1, 2); STG_B(buf ^ 1, t + 1, 3); }
    __builtin_amdgcn_s_barrier();
    asm volatile("s_waitcnt lgkmcnt(0)" ::: "memory");
    __builtin_amdgcn_s_setprio(1);
#pragma unroll
    for (int mi = 0; mi < 4; ++mi)
#pragma unroll
      for (int ni = 0; ni < 4; ++ni)
        acc[mi][ni] = __builtin_amdgcn_mfma_f32_16x16x32_bf16(af[mi], bf1[ni], acc[mi][ni], 0, 0, 0);
    __builtin_amdgcn_s_setprio(0);
    __builtin_amdgcn_s_barrier();

    // ---- phase 3: kk1, A-odd; stage A q1,q3 LAST ----
#pragma unroll
    for (int mi = 0; mi < 4; ++mi)
      af[mi] = *(const s16x8*)(sa + (wm * 128 + (4 + mi) * 16 + lr) * 128 + c1x);
    if (pf) { STG_A(buf ^ 1, t + 1, 1); STG_A(buf ^ 1, t + 1, 3); }
    __builtin_amdgcn_s_barrier();
    asm volatile("s_waitcnt lgkmcnt(0)" ::: "memory");
    __builtin_amdgcn_s_setprio(1);
#pragma unroll
    for (int mi = 0; mi < 4; ++mi)
#pragma unroll
      for (int ni = 0; ni < 4; ++ni)
        acc[4 + mi][ni] = __builtin_amdgcn_mfma_f32_16x16x32_bf16(af[mi], bf1[ni], acc[4 + mi][ni], 0, 0, 0);
    __builtin_amdgcn_s_setprio(0);
    if (pf) {
      asm volatile("s_waitcnt vmcnt(2)" ::: "memory");
    } else {
      asm volatile("s_waitcnt vmcnt(0)" ::: "memory");
    }
    __builtin_amdgcn_s_barrier();
  }
#undef STG_A
#undef STG_B

  if (bf16out) {
    unsigned short* Co = (unsigned short*)Cc;
#pragma unroll
    for (int mi = 0; mi < 8; ++mi)
#pragma unroll
      for (int ni = 0; ni < 4; ++ni) {
        size_t base = (size_t)(m0 + wm * 128 + mi * 16 + lg * 4) * Nc + (n0 + wn * 64 + ni * 16 + lr);
#pragma unroll
        for (int i = 0; i < 4; ++i)
          Co[base + (size_t)i * Nc] = f2bf(acc[mi][ni][i]);
      }
  } else {
    float* Co = (float*)Cc;
#pragma unroll
    for (int mi = 0; mi < 8; ++mi)
#pragma unroll
      for (int ni = 0; ni < 4; ++ni) {
        size_t base = (size_t)(m0 + wm * 128 + mi * 16 + lg * 4) * Nc + (n0 + wn * 64 + ni * 16 + lr);
#pragma unroll
        for (int i = 0; i < 4; ++i)
          Co[base + (size_t)i * Nc] = acc[mi][ni][i];
      }
  }
}

// ---------- GEMM3: 256x160 tile -> 16m x 16n = 256 blocks = exactly 1/CU (round-15 proven) ----------
__global__ __launch_bounds__(512, 2) void k_gemm3(const unsigned short* __restrict__ A,
                                                  const unsigned short* __restrict__ Bw,
                                                  float* __restrict__ Cc) {
  const int Nc = 2560, Kd = 2048;
  __shared__ unsigned short shA[2][256 * 64];
  __shared__ unsigned short shB[2][160 * 64];
  const int tid = threadIdx.x, w = tid >> 6, l = tid & 63;
  const int xcd = blockIdx.x & 7, loc = blockIdx.x >> 3;  // loc 0..31
  const int m0 = (xcd * 2 + (loc >> 4)) * 256;            // 16 m-tiles, 2 per XCD
  const int n0 = (loc & 15) * 160;                        // 16 n-tiles

  const int srow = l >> 3;                      // 0..7
  const int sw_colb = (((l & 7) ^ srow) << 4);  // inverse-swizzled source col (bytes)
  const int wrow = w * 8;
  const int NT = Kd >> 6;  // 32

  // per-wave issue count: A x4 + B x2 + (w<4 ? B x1 : 0) = 7 or 6
#define GSTAGE3(buf, t)                                                                     \
  {                                                                                         \
    const size_t kt = (size_t)(t) << 6;                                                     \
    _Pragma("unroll") for (int r = 0; r < 4; ++r) {                                         \
      const char* srcA = (const char*)A +                                                   \
          ((size_t)(m0 + r * 64 + wrow + srow) * Kd + kt) * 2 + sw_colb;                    \
      __builtin_amdgcn_global_load_lds(                                                     \
          (__attribute__((address_space(1))) void*)srcA,                                    \
          (__attribute__((address_space(3))) void*)((char*)&shA[buf][0] + r * 8192 + w * 1024), \
          16, 0, 0);                                                                        \
    }                                                                                       \
    _Pragma("unroll") for (int r = 0; r < 2; ++r) {                                         \
      const char* srcB = (const char*)Bw +                                                  \
          ((size_t)(n0 + r * 64 + wrow + srow) * Kd + kt) * 2 + sw_colb;                    \
      __builtin_amdgcn_global_load_lds(                                                     \
          (__attribute__((address_space(1))) void*)srcB,                                    \
          (__attribute__((address_space(3))) void*)((char*)&shB[buf][0] + r * 8192 + w * 1024), \
          16, 0, 0);                                                                        \
    }                                                                                       \
    if (w < 4) {                                                                            \
      const char* srcB = (const char*)Bw +                                                  \
          ((size_t)(n0 + 128 + wrow + srow) * Kd + kt) * 2 + sw_colb;                       \
      __builtin_amdgcn_global_load_lds(                                                     \
          (__attribute__((address_space(1))) void*)srcB,                                    \
          (__attribute__((address_space(3))) void*)((char*)&shB[buf][0] + 16384 + w * 1024), \
          16, 0, 0);                                                                        \
    }                                                                                       \
  }

  const int wm = w >> 1, wn = w & 1;  // 4M x 2N wave grid, per-wave 64x80
  const int lr = l & 15, lg = l >> 4;
  const int rswz = (lr & 7) << 4;
  f32x4 acc[4][5] = {};

  GSTAGE3(0, 0);

  for (int t = 0; t < NT; ++t) {
    const int buf = t & 1;
    if (t + 1 < NT) {
      GSTAGE3(buf ^ 1, t + 1);
      if (w < 4) {
        asm volatile("s_waitcnt vmcnt(7)" ::: "memory");
      } else {
        asm volatile("s_waitcnt vmcnt(6)" ::: "memory");
      }
    } else {
      asm volatile("s_waitcnt vmcnt(0)" ::: "memory");
    }
    __builtin_amdgcn_s_barrier();

    const char* sa = (const char*)&shA[buf][0];
    const char* sb = (const char*)&shB[buf][0];
#pragma unroll
    for (int kk = 0; kk < 2; ++kk) {
      const int cbx = (kk * 64 + lg * 16) ^ rswz;
      s16x8 af[4], bfr[5];
#pragma unroll
      for (int mi = 0; mi < 4; ++mi)
        af[mi] = *(const s16x8*)(sa + (wm * 64 + mi * 16 + lr) * 128 + cbx);
#pragma unroll
      for (int ni = 0; ni < 5; ++ni)
        bfr[ni] = *(const s16x8*)(sb + (wn * 80 + ni * 16 + lr) * 128 + cbx);
      __builtin_amdgcn_s_setprio(1);
#pragma unroll
      for (int mi = 0; mi < 4; ++mi)
#pragma unroll
        for (int ni = 0; ni < 5; ++ni)
          acc[mi][ni] = __builtin_amdgcn_mfma_f32_16x16x32_bf16(af[mi], bfr[ni], acc[mi][ni], 0, 0, 0);
      __builtin_amdgcn_s_setprio(0);
    }
    __builtin_amdgcn_s_barrier();
  }
#undef GSTAGE3

#pragma unroll
  for (int mi = 0; mi < 4; ++mi)
#pragma unroll
    for (int ni = 0; ni < 5; ++ni) {
      size_t base = (size_t)(m0 + wm * 64 + mi * 16 + lg * 4) * Nc + (n0 + wn * 80 + ni * 16 + lr);
#pragma unroll
      for (int i = 0; i < 4; ++i)
        Cc[base + (size_t)i * Nc] = acc[mi][ni][i];
    }
}

// ---------- fused RMSNorm+RoPE (blocks 0..4095) and V-transpose (blocks 4096..5119) ----------
__global__ __launch_bounds__(256) void k_post(const unsigned short* __restrict__ Y,
                                              const float* __restrict__ qsc,
                                              const float* __restrict__ ksc,
                                              const int* __restrict__ pos,
                                              unsigned short* __restrict__ Q,
                                              unsigned short* __restrict__ Kb,
                                              unsigned short* __restrict__ VT) {
  __shared__ float s_sin[128], s_cos[128];
  __shared__ unsigned short ttile[64][65];
  const int tid = threadIdx.x;
  if (blockIdx.x < 4096) {
    // ---- RMSNorm + RoPE ----
    const int bt = blockIdx.x;
    const int b = bt >> 11, t = bt & (TB - 1);
    float p = (float)pos[bt];
    if (tid < 128) {
      float fr = (float)tid * (1.0f / 128.0f);
      float inv_ts = __expf(fr * -9.210340371976184f);  // 10000^-fr
      float ang = p * inv_ts;
      float sv, cv;
      sincosf(ang, &sv, &cv);
      s_sin[tid] = sv;
      s_cos[tid] = cv;
    }
    __syncthreads();
    const int w = tid >> 6, l = tid & 63;
    const int jj0 = (l & 31) * 4;
    for (int sidx = w; sidx < 12; sidx += 4) {  // 0..7 q heads, 8..11 k heads
      const unsigned short* src = Y + (size_t)bt * 4096 + sidx * 256;
      u16x4 vb = *(const u16x4*)&src[l * 4];
      float v[4];
#pragma unroll
      for (int j = 0; j < 4; ++j) v[j] = bf2f(vb[j]);
      float ss = v[0] * v[0] + v[1] * v[1] + v[2] * v[2] + v[3] * v[3];
#pragma unroll
      for (int d = 1; d < 64; d <<= 1) ss += __shfl_xor(ss, d);
      float rs = rsqrtf(ss * (1.0f / 256.0f) + 1e-6f);
      const float* scp = (sidx < 8) ? qsc : ksc;
      float nv[4], res[4];
#pragma unroll
      for (int j = 0; j < 4; ++j) nv[j] = v[j] * rs * (1.0f + scp[l * 4 + j]);
#pragma unroll
      for (int j = 0; j < 4; ++j) {
        float o = __shfl_xor(nv[j], 32);
        float sn = s_sin[jj0 + j], cs = s_cos[jj0 + j];
        res[j] = (l < 32) ? (nv[j] * cs - o * sn) : (nv[j] * cs + o * sn);
      }
      float qs = (sidx < 8) ? 0.0625f : 1.0f;  // H^-0.5 = 1/16 folded into q
      u16x4 ob;
#pragma unroll
      for (int j = 0; j < 4; ++j) ob[j] = f2bf(res[j] * qs);
      if (sidx < 8) {
        size_t di = ((size_t)(b * NQ + sidx) * TB + t) * HDIM + l * 4;
        *(u16x4*)&Q[di] = ob;
      } else {
        size_t di = ((size_t)(b * NKV + (sidx - 8)) * TB + t) * HDIM + l * 4;
        *(u16x4*)&Kb[di] = ob;
      }
    }
  } else {
    // ---- V transpose: Y v-channels -> VT[B][NKV][H][T] ----
    const int zz = blockIdx.x - 4096;  // 1024 blocks: (t0 32) x (h0 4) x (bn 8)
    const int t0 = (zz & 31) * 64;
    const int h0 = ((zz >> 5) & 3) * 64;
    const int z = zz >> 7;  // b*4+kh
    const int bq = z >> 2, kh = z & 3;
#pragma unroll
    for (int rep = 0; rep < 16; ++rep) {
      int idx = rep * 256 + tid;
      int tr = idx >> 6, hc = idx & 63;
      ttile[tr][hc] = Y[(size_t)(bq * TB + t0 + tr) * 4096 + 3072 + kh * 256 + h0 + hc];
    }
    __syncthreads();
#pragma unroll
    for (int rep = 0; rep < 16; ++rep) {
      int idx = rep * 256 + tid;
      int hr = idx >> 6, tc = idx & 63;
      VT[((size_t)z * 256 + h0 + hr) * TB + t0 + tc] = ttile[tc][hr];
    }
  }
}

// ---------- flash attention: counted-vmcnt pipeline, per-lane lsum, defer-rescale ----------
__global__ __launch_bounds__(256, 2) void k_attn(const unsigned short* __restrict__ Q,
                                                 const unsigned short* __restrict__ Kb,
                                                 const unsigned short* __restrict__ VT,
                                                 unsigned short* __restrict__ ENC) {
  __shared__ unsigned short shK[2][32 * 256];  // [s-row][h], 512B rows, XOR-swizzled
  __shared__ unsigned short shV[2][256 * 32];  // [h-row][s], 64B rows
  __shared__ unsigned short Pb[4][16 * 40];    // 80B rows
  const int tid = threadIdx.x, w = tid >> 6, l = tid & 63;
  const int bn = blockIdx.y;
  const int b = bn >> 3, n = bn & 7, kh = n >> 1;
  // load-balance pairing: consecutive dispatch indices get complementary step counts
  const int xr = blockIdx.x;
  const int xs = (xr & 1) ? (31 - (xr >> 1)) : (xr >> 1);
  const int t0b = xs * 64;
  const int t0 = t0b + w * 16;
  const int lr = l & 15, lg = l >> 4;
  const unsigned short* qp = Q + ((size_t)bn * TB + t0) * HDIM;
  const char* kbase = (const char*)(Kb + ((size_t)(b * NKV + kh) * TB) * HDIM);
  const char* vbase = (const char*)(VT + ((size_t)(b * NKV + kh) * HDIM) * TB);

  s16x8 aq[8];
#pragma unroll
  for (int kk = 0; kk < 8; ++kk)
    aq[kk] = *(const s16x8*)&qp[lr * HDIM + kk * 32 + lg * 8];

  f32x4 o[16] = {};
  float mrow[4], lsum[4];  // lsum is PER-LANE partial; reduced across 16 lanes at epilogue
#pragma unroll
  for (int i = 0; i < 4; ++i) { mrow[i] = -__builtin_inff(); lsum[i] = 0.f; }

  int lo = t0b - (WIN - 1);
  if (lo < 0) lo = 0;
  lo &= ~31;
  const int nsteps = (t0b + 32 - lo) / 32 + 1;

  const int k_row = (w << 1) + (l >> 5);
  const int k_colb = (l & 31) * 16;
  const int v_row = (w << 4) + (l >> 2);
  const int v_colb = (l & 3) * 16;
#define STAGE(buf, s0)                                                                       \
  {                                                                                          \
    _Pragma("unroll") for (int r = 0; r < 4; ++r) {                                          \
      int row = r * 8 + k_row;                                                               \
      int scol = k_colb ^ ((row & 7) << 4);                                                  \
      const char* src = kbase + (size_t)((s0) + row) * 512 + scol;                           \
      __builtin_amdgcn_global_load_lds(                                                      \
          (__attribute__((address_space(1))) void*)src,                                      \
          (__attribute__((address_space(3))) void*)((char*)&shK[buf][0] + r * 4096 + w * 1024), \
          16, 0, 0);                                                                         \
    }                                                                                        \
    _Pragma("unroll") for (int r = 0; r < 4; ++r) {                                          \
      int row = r * 64 + v_row;                                                              \
      const char* src = vbase + (size_t)row * (TB * 2) + (size_t)(s0) * 2 + v_colb;          \
      __builtin_amdgcn_global_load_lds(                                                      \
          (__attribute__((address_space(1))) void*)src,                                      \
          (__attribute__((address_space(3))) void*)((char*)&shV[buf][0] + r * 4096 + w * 1024), \
          16, 0, 0);                                                                         \
    }                                                                                        \
  }

  STAGE(0, lo);

  for (int step = 0; step < nsteps; ++step) {
    const int s0 = lo + step * 32;
    const int buf = step & 1;
    // issue next-tile loads FIRST, then counted wait: tile `step` confirmed resident,
    // tile step+1's 8 loads stay in flight across both barriers (T3/T4).
    if (step + 1 < nsteps) {
      STAGE(buf ^ 1, s0 + 32);
      asm volatile("s_waitcnt vmcnt(8)" ::: "memory");
    } else {
      asm volatile("s_waitcnt vmcnt(0)" ::: "memory");
    }
    __builtin_amdgcn_s_barrier();

    const bool active = (s0 <= t0 + 15) && (s0 + 31 >= t0 - (WIN - 1));
    if (active) {
      // QK^T from LDS (swizzled read)
      f32x4 sacc[2] = {};
      const char* kt = (const char*)&shK[buf][0];
      const int swz = (lr & 7) << 4;
#pragma unroll
      for (int cb = 0; cb < 2; ++cb) {
        const int rb = (cb * 16 + lr) * 512;
        s16x8 bk[8];
#pragma unroll
        for (int kk = 0; kk < 8; ++kk)
          bk[kk] = *(const s16x8*)(kt + rb + ((kk * 64 + lg * 16) ^ swz));
        __builtin_amdgcn_s_setprio(1);
#pragma unroll
        for (int kk = 0; kk < 8; ++kk)
          sacc[cb] = __builtin_amdgcn_mfma_f32_16x16x32_bf16(aq[kk], bk[kk], sacc[cb], 0, 0, 0);
        __builtin_amdgcn_s_setprio(0);
      }
      // mask (skipped for interior steps: wave-uniform branch)
      float svA_[4], svB_[4];
      const bool nomask = (s0 + 31 <= t0) && (s0 >= t0 - (WIN - 16));
      if (nomask) {
#pragma unroll
        for (int i = 0; i < 4; ++i) { svA_[i] = sacc[0][i]; svB_[i] = sacc[1][i]; }
      } else {
#pragma unroll
        for (int i = 0; i < 4; ++i) {
          int trow = t0 + lg * 4 + i;
          int sA = s0 + lr, sB = s0 + 16 + lr;
          svA_[i] = ((sA <= trow) && (trow - sA < WIN)) ? sacc[0][i] : KMASK;
          svB_[i] = ((sB <= trow) && (trow - sB < WIN)) ? sacc[1][i] : KMASK;
        }
      }
      // reduce-free threshold check (T13): only reduce+rescale when some score
      // exceeds its row's running max + 8
      bool ok = true;
#pragma unroll
      for (int i = 0; i < 4; ++i)
        ok = ok && (svA_[i] <= mrow[i] + 8.f) && (svB_[i] <= mrow[i] + 8.f);
      if (!__all(ok)) {
        float r_[4];
#pragma unroll
        for (int i = 0; i < 4; ++i) {
          float mx = fmaxf(svA_[i], svB_[i]);
#pragma unroll
          for (int d = 1; d < 16; d <<= 1) mx = fmaxf(mx, __shfl_xor(mx, d));
          float mnew = fmaxf(mrow[i], mx);
          r_[i] = __expf(mrow[i] - mnew);
          lsum[i] *= r_[i];
          mrow[i] = mnew;
        }
#pragma unroll
        for (int hb = 0; hb < 16; ++hb)
#pragma unroll
          for (int i = 0; i < 4; ++i) o[hb][i] *= r_[i];
      }
      // P = exp(S - m); per-lane lsum accumulation (no per-step reduce)
#pragma unroll
      for (int i = 0; i < 4; ++i) {
        float pa = __expf(svA_[i] - mrow[i]);
        float pb = __expf(svB_[i] - mrow[i]);
        lsum[i] += pa + pb;
        int row = lg * 4 + i;
        Pb[w][row * 40 + lr] = f2bf(pa);
        Pb[w][row * 40 + 16 + lr] = f2bf(pb);
      }
      asm volatile("s_waitcnt lgkmcnt(0)" ::: "memory");
      s16x8 pfrag = *(const s16x8*)&Pb[w][lr * 40 + lg * 8];
      // PV from LDS V-tile
      const char* vt = (const char*)&shV[buf][0];
      s16x8 vb[16];
#pragma unroll
      for (int hb = 0; hb < 16; ++hb)
        vb[hb] = *(const s16x8*)(vt + (hb * 16 + lr) * 64 + lg * 16);
      __builtin_amdgcn_s_setprio(1);
#pragma unroll
      for (int hb = 0; hb < 16; ++hb)
        o[hb] = __builtin_amdgcn_mfma_f32_16x16x32_bf16(pfrag, vb[hb], o[hb], 0, 0, 0);
      __builtin_amdgcn_s_setprio(0);
    }
    __builtin_amdgcn_s_barrier();  // protect dbuf overwrite by next step's STAGE
  }
#undef STAGE

  // epilogue: reduce per-lane lsum across the row's 16 lanes
#pragma unroll
  for (int i = 0; i < 4; ++i) {
    float s = lsum[i];
#pragma unroll
    for (int d = 1; d < 16; d <<= 1) s += __shfl_xor(s, d);
    lsum[i] = s;
  }
#pragma unroll
  for (int i = 0; i < 4; ++i) {
    int trow = t0 + lg * 4 + i;
    float inv = 1.0f / lsum[i];
    size_t rb = (size_t)(b * TB + trow) * 2048 + n * HDIM;
#pragma unroll
    for (int hb = 0; hb < 16; ++hb)
      ENC[rb + hb * 16 + lr] = f2bf(o[hb][i] * inv);
  }
}

extern "C" void kernel_launch(void* const* d_in, const int* in_sizes, int n_in,
                              void* d_out, int out_size, void* d_ws, size_t ws_size,
                              hipStream_t stream) {
  (void)in_sizes; (void)n_in; (void)out_size; (void)ws_size;
  const float* x = (const float*)d_in[0];
  const float* q_w = (const float*)d_in[1];
  const float* kv_w = (const float*)d_in[2];
  const float* qsc = (const float*)d_in[3];
  const float* ksc = (const float*)d_in[4];
  const float* out_w = (const float*)d_in[5];
  const int* pos = (const int*)d_in[6];
  float* out = (float*)d_out;

  char* ws = (char*)d_ws;
  unsigned short* W1 = (unsigned short*)(ws);              // 4096x2560 bf16 (20.97 MB)
  unsigned short* W3 = (unsigned short*)(ws + 20971520);   // 2560x2048 bf16 (10.49 MB)
  unsigned short* XB = (unsigned short*)(ws + 31457280);   // 4096x2560 bf16 (20.97 MB)
  unsigned short* Y = (unsigned short*)(ws + 52428800);    // 4096x4096 bf16 (33.5 MB)
  unsigned short* KB = (unsigned short*)(ws + 119537664);  // 2x4x2048x256 bf16 (8.39 MB)
  unsigned short* VT = (unsigned short*)(ws + 127926272);  // 2x4x256x2048 bf16 (8.39 MB)
  unsigned short* Qb = XB;                                 // reuse XB after GEMM1
  unsigned short* ENC = (unsigned short*)(ws + 90000000);  // after Y region (distinct)

  // fused prep: W1 pack (10240) + W3 transpose (5120) + x cvt (10240)
  k_prep<<<dim3(25600), 256, 0, stream>>>(q_w, kv_w, out_w, x, W1, W3, XB);
  // GEMM1: M=4096 (16 m-tiles), N=4096 (16 n-tiles) -> 256 blocks, XCD region 4m x 8n
  k_gemm<<<dim3(256), 512, 0, stream>>>(XB, W1, Y, 4096, DIM, 8, 1);
  // fused normrope (4096 blocks) + vtrans (1024 blocks)
  k_post<<<dim3(5120), 256, 0, stream>>>(Y, qsc, ksc, pos, Qb, KB, VT);
  k_attn<<<dim3(32, 16), 256, 0, stream>>>(Qb, KB, VT, ENC);
  // GEMM3: 256x160 tile -> 16 x 16 = 256 blocks, exactly 1/CU
  k_gemm3<<<dim3(256), 512, 0, stream>>>(ENC, W3, out);
}